// Round 6
// baseline (282.993 us; speedup 1.0000x reference)
//
#include <hip/hip_runtime.h>
#include <math.h>

#define BATCH 512
#define CCH   64
#define NND   32
#define VOC   100
#define DEMB  32
#define HID   64
#define NEDGE 256
#define NT    37

// ws float-word layout:
//   WS_A    [0    .. 1024)  dense normalized adjacency Ahat[32][32] (row=dst)
//   WS_WLZ  [1024 .. 3072)  Wz @ Lz[:64]  (32 x 64)
//   WS_WLH  [3072 .. 5120)  Wh @ Lh[:64]  (32 x 64)
//   WS_CBZ  [5120 .. 5184)  bz @ Lz[:64] + lbz   (64)
//   WS_CBH  [5184 .. 5248)  bh @ Lh[:64] + lbh   (64)
//   WS_PC   [5248 .. 5286)  prefix sums of softmax(att): pc[l] = sum_{t<l} p_t
#define WS_A    0
#define WS_WLZ  1024
#define WS_WLH  3072
#define WS_CBZ  5120
#define WS_CBH  5184
#define WS_PC   5248

__global__ __launch_bounds__(256)
void a3_setup(const int* __restrict__ tei, const float* __restrict__ att,
              const float* __restrict__ Wz, const float* __restrict__ Lz,
              const float* __restrict__ bz, const float* __restrict__ lbz,
              const float* __restrict__ Wh, const float* __restrict__ Lh,
              const float* __restrict__ bh, const float* __restrict__ lbh,
              float* __restrict__ ws) {
    __shared__ int   ldeg[NND];
    __shared__ float ldinv[NND];
    __shared__ float lA[NND][NND];
    __shared__ float le[NT];

    const int tid = threadIdx.x;   // 256 threads; NEDGE == 256

    if (tid < NND) ldeg[tid] = 1;                 // self-loop
#pragma unroll
    for (int i = 0; i < 4; ++i) ((float*)lA)[tid + 256 * i] = 0.f;
    if (tid < NT) le[tid] = att[tid];
    const int s_e = tei[tid];
    const int d_e = tei[NEDGE + tid];
    __syncthreads();

    atomicAdd(&ldeg[d_e], 1);
    __syncthreads();
    if (tid < NND) ldinv[tid] = rsqrtf((float)ldeg[tid]);
    __syncthreads();
    atomicAdd(&lA[d_e][s_e], ldinv[s_e] * ldinv[d_e]);
    if (tid < NND) atomicAdd(&lA[tid][tid], ldinv[tid] * ldinv[tid]);
    __syncthreads();

    // A -> ws
#pragma unroll
    for (int i = 0; i < 4; ++i) ws[WS_A + tid + 256 * i] = ((float*)lA)[tid + 256 * i];

    // WL = W @ L_top : 2048 outputs each; thread owns hd = tid&63, e = tid>>6 + 4i
    {
        const int hd = tid & 63;
        const int e0 = tid >> 6;
        float az[8], ah[8];
#pragma unroll
        for (int i = 0; i < 8; ++i) { az[i] = 0.f; ah[i] = 0.f; }
        for (int k = 0; k < HID; ++k) {
            const float lz = Lz[k * HID + hd];
            const float lh = Lh[k * HID + hd];
#pragma unroll
            for (int i = 0; i < 8; ++i) {
                const int e = e0 + 4 * i;
                az[i] = fmaf(Wz[e * HID + k], lz, az[i]);
                ah[i] = fmaf(Wh[e * HID + k], lh, ah[i]);
            }
        }
#pragma unroll
        for (int i = 0; i < 8; ++i) {
            const int o = (e0 + 4 * i) * HID + hd;
            ws[WS_WLZ + o] = az[i];
            ws[WS_WLH + o] = ah[i];
        }
    }

    // cb = b @ L_top + lb
    if (tid < HID) {
        float sz = lbz[tid], sh = lbh[tid];
        for (int k = 0; k < HID; ++k) {
            sz = fmaf(bz[k], Lz[k * HID + tid], sz);
            sh = fmaf(bh[k], Lh[k * HID + tid], sh);
        }
        ws[WS_CBZ + tid] = sz;
        ws[WS_CBH + tid] = sh;
    }

    // softmax prefix table: pc[l] = sum_{t<l} softmax(att)_t, l = 0..37
    if (tid <= NT) {
        float m = le[0];
        for (int t = 1; t < NT; ++t) m = fmaxf(m, le[t]);
        float tot = 0.f, pre = 0.f;
        for (int t = 0; t < NT; ++t) {
            const float e = expf(le[t] - m);
            tot += e;
            if (t < tid) pre += e;
        }
        ws[WS_PC + tid] = pre / tot;
    }
}

__global__ __launch_bounds__(256, 2)
void a3_main(const int* __restrict__ xbg, const int* __restrict__ LOSb,
             const float* __restrict__ emb,
             const float* __restrict__ Wc1, const float* __restrict__ bc1,
             const float* __restrict__ Wc2, const float* __restrict__ bc2,
             const float* __restrict__ ws, float* __restrict__ out) {
    __shared__ int   xb[CCH];
    __shared__ float sA[NND][NND];          // 4 KB
    __shared__ float xe[CCH][DEMB];         // 8 KB
    __shared__ float xa[CCH][DEMB];         // 8 KB
    __shared__ float sWL[2][DEMB][HID];     // 16 KB (z, h)
    __shared__ float scb[2][HID];
    __shared__ float part[4][HID];
    __shared__ float pooled[HID];
    __shared__ float h1s[2 * HID];

    const int b   = blockIdx.x;
    const int tid = threadIdx.x;

    // ---- stage constants + per-batch indices ----
    if (tid < CCH) xb[tid] = xbg[b * CCH + tid];
#pragma unroll
    for (int i = 0; i < 4; ++i) ((float*)sA)[tid + 256 * i] = ws[WS_A + tid + 256 * i];
#pragma unroll
    for (int i = 0; i < 8; ++i) {
        ((float*)sWL)[tid + 256 * i]        = ws[WS_WLZ + tid + 256 * i];
        ((float*)sWL)[2048 + tid + 256 * i] = ws[WS_WLH + tid + 256 * i];
    }
    if (tid < 2 * HID) ((float*)scb)[tid] = ws[WS_CBZ + tid];
    const int   los = LOSb[b];
    const float cA  = ws[WS_PC + los];
    const float cD  = 1.0f - cA;
    __syncthreads();

    // ---- gather embeddings (rows 0..31 = ad, 32..63 = dis) ----
#pragma unroll
    for (int i = 0; i < 8; ++i) {
        const int el = tid + 256 * i;
        const int c = el >> 5, k = el & 31;
        xe[c][k] = emb[(c * VOC + xb[c]) * DEMB + k];
    }
    __syncthreads();

    // ---- xa = Ahat @ xe  (per temporal variant; shared by both gates) ----
#pragma unroll
    for (int i = 0; i < 8; ++i) {
        const int o = tid + 256 * i;       // 2048 outputs
        const int r = o >> 5, k = o & 31;
        const int n = r & 31, vb = r & 32;
        float s = 0.f;
#pragma unroll
        for (int q = 0; q < NND; ++q) s = fmaf(sA[n][q], xe[vb | q][k], s);
        xa[r][k] = s;
    }
    __syncthreads();

    // ---- gates + weighted accumulate (fused GEMM with precomputed W@L) ----
    const int hd = tid & 63;
    const int rg = tid >> 6;               // wave-uniform row group
    float psum = 0.f;
#pragma unroll
    for (int j = 0; j < 16; ++j) {
        const int r = rg + 4 * j;          // 0..63
        float zl = scb[0][hd], hl = scb[1][hd];
#pragma unroll
        for (int k = 0; k < DEMB; ++k) {
            const float x = xa[r][k];      // wave-uniform broadcast
            zl = fmaf(x, sWL[0][k][hd], zl);
            hl = fmaf(x, sWL[1][k][hd], hl);
        }
        const float Z  = 1.0f / (1.0f + expf(-zl));
        const float Ht = tanhf(hl);
        const float w  = (r < NND) ? cA : cD;
        psum = fmaf(w, (1.0f - Z) * Ht, psum);
    }
    part[rg][hd] = psum;
    __syncthreads();

    // ---- pooled = mean over nodes of accumulated cell ----
    if (tid < HID)
        pooled[tid] = (part[0][tid] + part[1][tid] + part[2][tid] + part[3][tid]) * (1.0f / NND);
    __syncthreads();

    // ---- head: relu(pooled @ Wc1 + bc1) . Wc2 + bc2 ----
    if (tid < 2 * HID) {
        float a = bc1[tid];
#pragma unroll
        for (int k = 0; k < HID; ++k) a = fmaf(pooled[k], Wc1[k * 2 * HID + tid], a);
        h1s[tid] = fmaxf(a, 0.f) * Wc2[tid];
    }
    __syncthreads();
    if (tid < 64) {
        float v = h1s[tid] + h1s[tid + 64];
#pragma unroll
        for (int off = 32; off; off >>= 1) v += __shfl_down(v, off);
        if (tid == 0) out[b] = v + bc2[0];
    }
}

extern "C" void kernel_launch(void* const* d_in, const int* in_sizes, int n_in,
                              void* d_out, int out_size, void* d_ws, size_t ws_size,
                              hipStream_t stream) {
    const int*   x_batch = (const int*)d_in[0];
    const int*   LOSb    = (const int*)d_in[1];
    const int*   tei     = (const int*)d_in[2];
    const float* emb     = (const float*)d_in[3];
    const float* Wz      = (const float*)d_in[4];
    const float* bz      = (const float*)d_in[5];
    const float* Wh      = (const float*)d_in[8];
    const float* bh      = (const float*)d_in[9];
    const float* Lz      = (const float*)d_in[10];
    const float* lbz     = (const float*)d_in[11];
    const float* Lh      = (const float*)d_in[14];
    const float* lbh     = (const float*)d_in[15];
    const float* att     = (const float*)d_in[16];
    const float* Wc1     = (const float*)d_in[17];
    const float* bc1     = (const float*)d_in[18];
    const float* Wc2     = (const float*)d_in[19];
    const float* bc2     = (const float*)d_in[20];
    float* ws   = (float*)d_ws;
    float* outp = (float*)d_out;

    hipLaunchKernelGGL(a3_setup, dim3(1), dim3(256), 0, stream,
                       tei, att, Wz, Lz, bz, lbz, Wh, Lh, bh, lbh, ws);
    hipLaunchKernelGGL(a3_main, dim3(BATCH), dim3(256), 0, stream,
                       x_batch, LOSb, emb, Wc1, bc1, Wc2, bc2, ws, outp);
}

// Round 7
// 190.387 us; speedup vs baseline: 1.4864x; 1.4864x over previous
//
#include <hip/hip_runtime.h>
#include <math.h>

#define BATCH 512
#define CCH   64
#define NND   32
#define VOC   100
#define DEMB  32
#define HID   64
#define NEDGE 256
#define NT    37

// Single fused kernel. No d_ws usage at all (round-6 evidence: per-lane reads
// from d_ws are serviced uncached at line granularity -> 212 MB HBM fetch,
// 256 us stall). All constants are rebuilt per block from d_in (L2-cached):
//   - Ahat (32x32 dense normalized adjacency) via LDS atomics over 256 edges
//   - WL = W @ L[:64] (the H0=0 collapse kills rows 64..127 of L)
//   - cb = b @ L[:64] + lb
//   - cA = prefix sum of softmax(att) at LOS[b]; cD = 1 - cA
__global__ __launch_bounds__(256)
void a3_fused(const int* __restrict__ xbg, const int* __restrict__ LOSb,
              const int* __restrict__ tei, const float* __restrict__ emb,
              const float* __restrict__ Wz, const float* __restrict__ bz,
              const float* __restrict__ Wh, const float* __restrict__ bh,
              const float* __restrict__ Lz, const float* __restrict__ lbz,
              const float* __restrict__ Lh, const float* __restrict__ lbh,
              const float* __restrict__ att,
              const float* __restrict__ Wc1, const float* __restrict__ bc1,
              const float* __restrict__ Wc2, const float* __restrict__ bc2,
              float* __restrict__ out) {
    __shared__ float sA[NND][NND];          // 4 KB
    __shared__ float xe[CCH][DEMB];         // 8 KB
    __shared__ float xa[CCH][DEMB];         // 8 KB
    __shared__ float sWL[2][DEMB][HID];     // 16 KB
    __shared__ float scb[2][HID];           // 512 B
    __shared__ float satt[NT];
    __shared__ int   xb[CCH];
    __shared__ int   sdeg[NND];
    __shared__ float sdinv[NND];
    __shared__ float part[4][HID];          // 1 KB
    __shared__ float pooled[HID];
    __shared__ float h1s[2 * HID];

    const int b   = blockIdx.x;
    const int tid = threadIdx.x;
    const int hd  = tid & 63;

    // ---- stage small per-batch + graph data ----
    if (tid < CCH) xb[tid] = xbg[b * CCH + tid];
    if (tid < NT)  satt[tid] = att[tid];
    if (tid < NND) sdeg[tid] = 1;                       // self-loop
#pragma unroll
    for (int i = 0; i < 4; ++i) ((float*)sA)[tid + 256 * i] = 0.f;
    const int s_e = tei[tid];                           // 256 edges, 256 threads
    const int d_e = tei[NEDGE + tid];
    __syncthreads();

    atomicAdd(&sdeg[d_e], 1);
    // embedding gather (reads xb, ready since last sync): 2048 elems, 8/thread
#pragma unroll
    for (int i = 0; i < 8; ++i) {
        const int el = tid + 256 * i;
        const int c = el >> 5, k = el & 31;
        xe[c][k] = emb[(c * VOC + xb[c]) * DEMB + k];
    }
    __syncthreads();
    if (tid < NND) sdinv[tid] = rsqrtf((float)sdeg[tid]);
    __syncthreads();
    atomicAdd(&sA[d_e][s_e], sdinv[s_e] * sdinv[d_e]);
    if (tid < NND) atomicAdd(&sA[tid][tid], sdinv[tid] * sdinv[tid]);

    // ---- WL = W @ L[:64]  (both gates), from d_in ----
    {
        const int e0 = tid >> 6;                        // wave id: 0..3
        float az[8], ah[8];
#pragma unroll
        for (int i = 0; i < 8; ++i) { az[i] = 0.f; ah[i] = 0.f; }
        for (int k = 0; k < HID; ++k) {
            const float lz = Lz[k * HID + hd];          // coalesced
            const float lh = Lh[k * HID + hd];
#pragma unroll
            for (int i = 0; i < 8; ++i) {
                const int e = e0 + 4 * i;
                az[i] = fmaf(Wz[e * HID + k], lz, az[i]);   // wave-uniform scalar
                ah[i] = fmaf(Wh[e * HID + k], lh, ah[i]);
            }
        }
#pragma unroll
        for (int i = 0; i < 8; ++i) {
            sWL[0][e0 + 4 * i][hd] = az[i];
            sWL[1][e0 + 4 * i][hd] = ah[i];
        }
    }

    // ---- cb = b @ L[:64] + lb ----
    if (tid < 2 * HID) {
        const int g = tid >> 6, c = tid & 63;
        const float* Lg  = g ? Lh  : Lz;
        const float* bg  = g ? bh  : bz;
        const float* lbg = g ? lbh : lbz;
        float s = lbg[c];
        for (int k = 0; k < HID; ++k) s = fmaf(bg[k], Lg[k * HID + c], s);
        scb[g][c] = s;
    }

    // ---- cA from softmax prefix (redundant per thread, all from LDS) ----
    const int los = LOSb[b];
    float cA;
    {
        float m = satt[0];
        for (int t = 1; t < NT; ++t) m = fmaxf(m, satt[t]);
        float tot = 0.f, pre = 0.f;
        for (int t = 0; t < NT; ++t) {
            const float e = expf(satt[t] - m);
            tot += e;
            if (t < los) pre += e;
        }
        cA = pre / tot;
    }
    const float cD = 1.0f - cA;
    __syncthreads();

    // ---- xa = Ahat @ xe (both temporal variants) ----
#pragma unroll
    for (int i = 0; i < 8; ++i) {
        const int o = tid + 256 * i;
        const int r = o >> 5, k = o & 31;
        const int n = r & 31, vb = r & 32;
        float s = 0.f;
#pragma unroll
        for (int q = 0; q < NND; ++q) s = fmaf(sA[n][q], xe[vb | q][k], s);
        xa[r][k] = s;
    }
    __syncthreads();

    // ---- gates + weighted accumulate ----
    const int rg = tid >> 6;
    float psum = 0.f;
#pragma unroll
    for (int j = 0; j < 16; ++j) {
        const int r = rg + 4 * j;
        float zl = scb[0][hd], hl = scb[1][hd];
#pragma unroll
        for (int k = 0; k < DEMB; ++k) {
            const float x = xa[r][k];                   // wave-uniform broadcast
            zl = fmaf(x, sWL[0][k][hd], zl);
            hl = fmaf(x, sWL[1][k][hd], hl);
        }
        const float Z  = 1.0f / (1.0f + expf(-zl));
        const float Ht = tanhf(hl);
        const float w  = (r < NND) ? cA : cD;
        psum = fmaf(w, (1.0f - Z) * Ht, psum);
    }
    part[rg][hd] = psum;
    __syncthreads();

    // ---- pool over nodes ----
    if (tid < HID)
        pooled[tid] = (part[0][tid] + part[1][tid] + part[2][tid] + part[3][tid]) * (1.0f / NND);
    __syncthreads();

    // ---- head ----
    if (tid < 2 * HID) {
        float a = bc1[tid];
#pragma unroll
        for (int k = 0; k < HID; ++k) a = fmaf(pooled[k], Wc1[k * 2 * HID + tid], a);
        h1s[tid] = fmaxf(a, 0.f) * Wc2[tid];
    }
    __syncthreads();
    if (tid < 64) {
        float v = h1s[tid] + h1s[tid + 64];
#pragma unroll
        for (int off = 32; off; off >>= 1) v += __shfl_down(v, off);
        if (tid == 0) out[b] = v + bc2[0];
    }
}

extern "C" void kernel_launch(void* const* d_in, const int* in_sizes, int n_in,
                              void* d_out, int out_size, void* d_ws, size_t ws_size,
                              hipStream_t stream) {
    const int*   x_batch = (const int*)d_in[0];
    const int*   LOSb    = (const int*)d_in[1];
    const int*   tei     = (const int*)d_in[2];
    const float* emb     = (const float*)d_in[3];
    const float* Wz      = (const float*)d_in[4];
    const float* bz      = (const float*)d_in[5];
    const float* Wh      = (const float*)d_in[8];
    const float* bh      = (const float*)d_in[9];
    const float* Lz      = (const float*)d_in[10];
    const float* lbz     = (const float*)d_in[11];
    const float* Lh      = (const float*)d_in[14];
    const float* lbh     = (const float*)d_in[15];
    const float* att     = (const float*)d_in[16];
    const float* Wc1     = (const float*)d_in[17];
    const float* bc1     = (const float*)d_in[18];
    const float* Wc2     = (const float*)d_in[19];
    const float* bc2     = (const float*)d_in[20];
    float* outp = (float*)d_out;

    hipLaunchKernelGGL(a3_fused, dim3(BATCH), dim3(256), 0, stream,
                       x_batch, LOSb, tei, emb, Wz, bz, Wh, bh, Lz, lbz, Lh, lbh,
                       att, Wc1, bc1, Wc2, bc2, outp);
}

// Round 8
// 176.729 us; speedup vs baseline: 1.6013x; 1.0773x over previous
//
#include <hip/hip_runtime.h>
#include <math.h>

#define BATCH 512
#define CCH   64
#define NND   32
#define VOC   100
#define DEMB  32
#define HID   64
#define NEDGE 256
#define NT    37

// Fused kernel, 2 batches per block (grid 256 = 1 block/CU).
// Rationale (r7 post-mortem): TCC counters are polluted by a co-tenant
// (310 MB "writes" vs our 2 KB; 15 ms dispatch outlier). SQ counters say
// memory-latency-stalled. So: halve per-batch global traffic + redundant
// W@L by processing 2 batches per block. No d_ws usage.
__global__ __launch_bounds__(256)
void a3_fused2(const int* __restrict__ xbg, const int* __restrict__ LOSb,
               const int* __restrict__ tei, const float* __restrict__ emb,
               const float* __restrict__ Wz, const float* __restrict__ bz,
               const float* __restrict__ Wh, const float* __restrict__ bh,
               const float* __restrict__ Lz, const float* __restrict__ lbz,
               const float* __restrict__ Lh, const float* __restrict__ lbh,
               const float* __restrict__ att,
               const float* __restrict__ Wc1, const float* __restrict__ bc1,
               const float* __restrict__ Wc2, const float* __restrict__ bc2,
               float* __restrict__ out) {
    __shared__ float sA[NND][NND];            // 4 KB
    __shared__ float xe[2][CCH][DEMB];        // 16 KB
    __shared__ float xa[2][CCH][DEMB];        // 16 KB
    __shared__ float sWL[2][DEMB][HID];       // 16 KB
    __shared__ float scb[2][HID];
    __shared__ float satt[NT];
    __shared__ int   xb[2][CCH];
    __shared__ int   sdeg[NND];
    __shared__ float sdinv[NND];
    __shared__ float part[2][4][HID];         // 2 KB
    __shared__ float pooled[2][HID];
    __shared__ float h1s[2][2 * HID];

    const int b0  = blockIdx.x * 2;
    const int tid = threadIdx.x;
    const int hd  = tid & 63;

    // ---- stage small data ----
    if (tid < 128) xb[tid >> 6][tid & 63] = xbg[(b0 + (tid >> 6)) * CCH + (tid & 63)];
    if (tid < NT)  satt[tid] = att[tid];
    if (tid < NND) sdeg[tid] = 1;             // self-loop
#pragma unroll
    for (int i = 0; i < 4; ++i) ((float*)sA)[tid + 256 * i] = 0.f;
    const int s_e = tei[tid];
    const int d_e = tei[NEDGE + tid];
    __syncthreads();

    atomicAdd(&sdeg[d_e], 1);
    // embedding gather: 4096 elems (2 batches), 16/thread
#pragma unroll 2
    for (int i = 0; i < 16; ++i) {
        const int el = tid + 256 * i;
        const int bi = el >> 11, c = (el >> 5) & 63, k = el & 31;
        xe[bi][c][k] = emb[(c * VOC + xb[bi][c]) * DEMB + k];
    }
    __syncthreads();
    if (tid < NND) sdinv[tid] = rsqrtf((float)sdeg[tid]);
    __syncthreads();
    atomicAdd(&sA[d_e][s_e], sdinv[s_e] * sdinv[d_e]);
    if (tid < NND) atomicAdd(&sA[tid][tid], sdinv[tid] * sdinv[tid]);

    // ---- WL = W @ L[:64] (both gates) ----
    {
        const int e0 = tid >> 6;              // wave id 0..3
        float az[8], ah[8];
#pragma unroll
        for (int i = 0; i < 8; ++i) { az[i] = 0.f; ah[i] = 0.f; }
        for (int k = 0; k < HID; ++k) {
            const float lz = Lz[k * HID + hd];
            const float lh = Lh[k * HID + hd];
#pragma unroll
            for (int i = 0; i < 8; ++i) {
                const int e = e0 + 4 * i;
                az[i] = fmaf(Wz[e * HID + k], lz, az[i]);
                ah[i] = fmaf(Wh[e * HID + k], lh, ah[i]);
            }
        }
#pragma unroll
        for (int i = 0; i < 8; ++i) {
            sWL[0][e0 + 4 * i][hd] = az[i];
            sWL[1][e0 + 4 * i][hd] = ah[i];
        }
    }

    // ---- cb = b @ L[:64] + lb ----
    if (tid < 2 * HID) {
        const int g = tid >> 6, c = tid & 63;
        const float* Lg  = g ? Lh  : Lz;
        const float* bg  = g ? bh  : bz;
        const float* lbg = g ? lbh : lbz;
        float s = lbg[c];
        for (int k = 0; k < HID; ++k) s = fmaf(bg[k], Lg[k * HID + c], s);
        scb[g][c] = s;
    }

    // ---- cA per batch from softmax prefix (redundant per thread) ----
    const int los0 = LOSb[b0];
    const int los1 = LOSb[b0 + 1];
    float cA0, cA1;
    {
        float m = satt[0];
        for (int t = 1; t < NT; ++t) m = fmaxf(m, satt[t]);
        float tot = 0.f, p0 = 0.f, p1 = 0.f;
        for (int t = 0; t < NT; ++t) {
            const float e = expf(satt[t] - m);
            tot += e;
            if (t < los0) p0 += e;
            if (t < los1) p1 += e;
        }
        cA0 = p0 / tot;
        cA1 = p1 / tot;
    }
    __syncthreads();

    // ---- xa = Ahat @ xe : 4096 outputs, 16/thread ----
#pragma unroll 2
    for (int i = 0; i < 16; ++i) {
        const int o = tid + 256 * i;
        const int bi = o >> 11, r = (o >> 5) & 63, k = o & 31;
        const int n = r & 31, vb = r & 32;
        float s = 0.f;
#pragma unroll
        for (int q = 0; q < NND; ++q) s = fmaf(sA[n][q], xe[bi][vb | q][k], s);
        xa[bi][r][k] = s;
    }
    __syncthreads();

    // ---- gates + weighted accumulate, both batches ----
    const int rg = tid >> 6;
#pragma unroll
    for (int bi = 0; bi < 2; ++bi) {
        const float cA = bi ? cA1 : cA0;
        const float cD = 1.0f - cA;
        float psum = 0.f;
#pragma unroll
        for (int j = 0; j < 16; ++j) {
            const int r = rg + 4 * j;
            float zl = scb[0][hd], hl = scb[1][hd];
#pragma unroll
            for (int k = 0; k < DEMB; ++k) {
                const float x = xa[bi][r][k];       // wave-uniform broadcast
                zl = fmaf(x, sWL[0][k][hd], zl);
                hl = fmaf(x, sWL[1][k][hd], hl);
            }
            const float Z  = 1.0f / (1.0f + expf(-zl));
            const float Ht = tanhf(hl);
            const float w  = (r < NND) ? cA : cD;
            psum = fmaf(w, (1.0f - Z) * Ht, psum);
        }
        part[bi][rg][hd] = psum;
    }
    __syncthreads();

    // ---- pool over nodes (128 outputs) ----
    if (tid < 128) {
        const int bi = tid >> 6, c = tid & 63;
        pooled[bi][c] = (part[bi][0][c] + part[bi][1][c] + part[bi][2][c] + part[bi][3][c])
                        * (1.0f / NND);
    }
    __syncthreads();

    // ---- head layer 1: 256 outputs (2 batches x 128) ----
    {
        const int bi = tid >> 7, c = tid & 127;
        float a = bc1[c];
#pragma unroll
        for (int k = 0; k < HID; ++k) a = fmaf(pooled[bi][k], Wc1[k * 2 * HID + c], a);
        h1s[bi][c] = fmaxf(a, 0.f) * Wc2[c];
    }
    __syncthreads();

    // ---- final reduction: wave 0 -> out[b0], wave 1 -> out[b0+1] ----
    if (tid < 128) {
        const int bi = tid >> 6, lane = tid & 63;
        float v = h1s[bi][lane] + h1s[bi][lane + 64];
#pragma unroll
        for (int off = 32; off; off >>= 1) v += __shfl_down(v, off);
        if (lane == 0) out[b0 + bi] = v + bc2[0];
    }
}

extern "C" void kernel_launch(void* const* d_in, const int* in_sizes, int n_in,
                              void* d_out, int out_size, void* d_ws, size_t ws_size,
                              hipStream_t stream) {
    const int*   x_batch = (const int*)d_in[0];
    const int*   LOSb    = (const int*)d_in[1];
    const int*   tei     = (const int*)d_in[2];
    const float* emb     = (const float*)d_in[3];
    const float* Wz      = (const float*)d_in[4];
    const float* bz      = (const float*)d_in[5];
    const float* Wh      = (const float*)d_in[8];
    const float* bh      = (const float*)d_in[9];
    const float* Lz      = (const float*)d_in[10];
    const float* lbz     = (const float*)d_in[11];
    const float* Lh      = (const float*)d_in[14];
    const float* lbh     = (const float*)d_in[15];
    const float* att     = (const float*)d_in[16];
    const float* Wc1     = (const float*)d_in[17];
    const float* bc1     = (const float*)d_in[18];
    const float* Wc2     = (const float*)d_in[19];
    const float* bc2     = (const float*)d_in[20];
    float* outp = (float*)d_out;

    hipLaunchKernelGGL(a3_fused2, dim3(BATCH / 2), dim3(256), 0, stream,
                       x_batch, LOSb, tei, emb, Wz, bz, Wh, bh, Lz, lbz, Lh, lbh,
                       att, Wc1, bc1, Wc2, bc2, outp);
}

// Round 9
// 119.545 us; speedup vs baseline: 2.3672x; 1.4783x over previous
//
#include <hip/hip_runtime.h>
#include <math.h>

#define BATCH 512
#define CCH   64
#define NND   32
#define VOC   100
#define DEMB  32
#define HID   64
#define NEDGE 256
#define NT    37

// Fused, 1 batch/block, occupancy-first (r8 post-mortem):
//  - TCC FETCH/WRITE are polluted by co-tenant traffic (~830 GB/s background);
//    the kernel is latency-bound with VGPR=256 -> 11% occupancy.
//  - This version forces VGPR<=128 via __launch_bounds__(256,4) and keeps
//    LDS <= 40KB so 4 blocks/CU fit: 16 waves/CU = ~50% occupancy.
__global__ __launch_bounds__(256, 4)
void a3_fused_occ(const int* __restrict__ xbg, const int* __restrict__ LOSb,
                  const int* __restrict__ tei, const float* __restrict__ emb,
                  const float* __restrict__ Wz, const float* __restrict__ bz,
                  const float* __restrict__ Wh, const float* __restrict__ bh,
                  const float* __restrict__ Lz, const float* __restrict__ lbz,
                  const float* __restrict__ Lh, const float* __restrict__ lbh,
                  const float* __restrict__ att,
                  const float* __restrict__ Wc1, const float* __restrict__ bc1,
                  const float* __restrict__ Wc2, const float* __restrict__ bc2,
                  float* __restrict__ out) {
    __shared__ float sA[NND][NND];          // 4 KB
    __shared__ float xe[CCH][DEMB];         // 8 KB
    __shared__ float xa[CCH][DEMB];         // 8 KB
    __shared__ float sWL[2][DEMB][HID];     // 16 KB
    __shared__ float scb[2][HID];           // 512 B
    __shared__ float satt[NT];
    __shared__ int   xb[CCH];
    __shared__ int   sdeg[NND];
    __shared__ float sdinv[NND];
    __shared__ float part[4][HID];          // 1 KB
    __shared__ float pooled[HID];
    __shared__ float h1s[2 * HID];

    const int b   = blockIdx.x;
    const int tid = threadIdx.x;
    const int hd  = tid & 63;

    // ---- stage small per-batch + graph data ----
    if (tid < CCH) xb[tid] = xbg[b * CCH + tid];
    if (tid < NT)  satt[tid] = att[tid];
    if (tid < NND) sdeg[tid] = 1;                       // self-loop
#pragma unroll
    for (int i = 0; i < 4; ++i) ((float*)sA)[tid + 256 * i] = 0.f;
    const int s_e = tei[tid];                           // 256 edges / 256 threads
    const int d_e = tei[NEDGE + tid];
    __syncthreads();

    atomicAdd(&sdeg[d_e], 1);
    // embedding gather: 2048 elems, 8/thread (limited unroll: register budget)
#pragma unroll 2
    for (int i = 0; i < 8; ++i) {
        const int el = tid + 256 * i;
        const int c = el >> 5, k = el & 31;
        xe[c][k] = emb[(c * VOC + xb[c]) * DEMB + k];
    }
    __syncthreads();
    if (tid < NND) sdinv[tid] = rsqrtf((float)sdeg[tid]);
    __syncthreads();
    atomicAdd(&sA[d_e][s_e], sdinv[s_e] * sdinv[d_e]);
    if (tid < NND) atomicAdd(&sA[tid][tid], sdinv[tid] * sdinv[tid]);

    // ---- WL = W @ L[:64]  (both gates); e0 = wave id (wave-uniform W loads) ----
    {
        const int e0 = tid >> 6;
        float az[8], ah[8];
#pragma unroll
        for (int i = 0; i < 8; ++i) { az[i] = 0.f; ah[i] = 0.f; }
#pragma unroll 4
        for (int k = 0; k < HID; ++k) {
            const float lz = Lz[k * HID + hd];          // coalesced
            const float lh = Lh[k * HID + hd];
#pragma unroll
            for (int i = 0; i < 8; ++i) {
                const int e = e0 + 4 * i;
                az[i] = fmaf(Wz[e * HID + k], lz, az[i]);   // wave-uniform scalar
                ah[i] = fmaf(Wh[e * HID + k], lh, ah[i]);
            }
        }
#pragma unroll
        for (int i = 0; i < 8; ++i) {
            sWL[0][e0 + 4 * i][hd] = az[i];
            sWL[1][e0 + 4 * i][hd] = ah[i];
        }
    }

    // ---- cb = b @ L[:64] + lb ----
    if (tid < 2 * HID) {
        const int g = tid >> 6, c = tid & 63;
        const float* Lg  = g ? Lh  : Lz;
        const float* bg  = g ? bh  : bz;
        const float* lbg = g ? lbh : lbz;
        float s = lbg[c];
#pragma unroll 4
        for (int k = 0; k < HID; ++k) s = fmaf(bg[k], Lg[k * HID + c], s);
        scb[g][c] = s;
    }

    // ---- cA from softmax prefix (redundant per thread, all from LDS) ----
    const int los = LOSb[b];
    float cA;
    {
        float m = satt[0];
        for (int t = 1; t < NT; ++t) m = fmaxf(m, satt[t]);
        float tot = 0.f, pre = 0.f;
        for (int t = 0; t < NT; ++t) {
            const float e = expf(satt[t] - m);
            tot += e;
            if (t < los) pre += e;
        }
        cA = pre / tot;
    }
    const float cD = 1.0f - cA;
    __syncthreads();

    // ---- xa = Ahat @ xe (both temporal variants) ----
#pragma unroll 2
    for (int i = 0; i < 8; ++i) {
        const int o = tid + 256 * i;
        const int r = o >> 5, k = o & 31;
        const int n = r & 31, vb = r & 32;
        float s = 0.f;
#pragma unroll
        for (int q = 0; q < NND; ++q) s = fmaf(sA[n][q], xe[vb | q][k], s);
        xa[r][k] = s;
    }
    __syncthreads();

    // ---- gates + weighted accumulate ----
    const int rg = tid >> 6;
    float psum = 0.f;
#pragma unroll 4
    for (int j = 0; j < 16; ++j) {
        const int r = rg + 4 * j;
        float zl = scb[0][hd], hl = scb[1][hd];
#pragma unroll
        for (int k = 0; k < DEMB; ++k) {
            const float x = xa[r][k];                   // wave-uniform broadcast
            zl = fmaf(x, sWL[0][k][hd], zl);
            hl = fmaf(x, sWL[1][k][hd], hl);
        }
        const float Z  = 1.0f / (1.0f + expf(-zl));
        const float Ht = tanhf(hl);
        const float w  = (r < NND) ? cA : cD;
        psum = fmaf(w, (1.0f - Z) * Ht, psum);
    }
    part[rg][hd] = psum;
    __syncthreads();

    // ---- pool over nodes ----
    if (tid < HID)
        pooled[tid] = (part[0][tid] + part[1][tid] + part[2][tid] + part[3][tid]) * (1.0f / NND);
    __syncthreads();

    // ---- head ----
    if (tid < 2 * HID) {
        float a = bc1[tid];
#pragma unroll 4
        for (int k = 0; k < HID; ++k) a = fmaf(pooled[k], Wc1[k * 2 * HID + tid], a);
        h1s[tid] = fmaxf(a, 0.f) * Wc2[tid];
    }
    __syncthreads();
    if (tid < 64) {
        float v = h1s[tid] + h1s[tid + 64];
#pragma unroll
        for (int off = 32; off; off >>= 1) v += __shfl_down(v, off);
        if (tid == 0) out[b] = v + bc2[0];
    }
}

extern "C" void kernel_launch(void* const* d_in, const int* in_sizes, int n_in,
                              void* d_out, int out_size, void* d_ws, size_t ws_size,
                              hipStream_t stream) {
    const int*   x_batch = (const int*)d_in[0];
    const int*   LOSb    = (const int*)d_in[1];
    const int*   tei     = (const int*)d_in[2];
    const float* emb     = (const float*)d_in[3];
    const float* Wz      = (const float*)d_in[4];
    const float* bz      = (const float*)d_in[5];
    const float* Wh      = (const float*)d_in[8];
    const float* bh      = (const float*)d_in[9];
    const float* Lz      = (const float*)d_in[10];
    const float* lbz     = (const float*)d_in[11];
    const float* Lh      = (const float*)d_in[14];
    const float* lbh     = (const float*)d_in[15];
    const float* att     = (const float*)d_in[16];
    const float* Wc1     = (const float*)d_in[17];
    const float* bc1     = (const float*)d_in[18];
    const float* Wc2     = (const float*)d_in[19];
    const float* bc2     = (const float*)d_in[20];
    float* outp = (float*)d_out;

    hipLaunchKernelGGL(a3_fused_occ, dim3(BATCH), dim3(256), 0, stream,
                       x_batch, LOSb, tei, emb, Wz, bz, Wh, bh, Lz, lbz, Lh, lbh,
                       att, Wc1, bc1, Wc2, bc2, outp);
}

// Round 10
// 35.345 us; speedup vs baseline: 8.0066x; 3.3823x over previous
//
#include <hip/hip_runtime.h>
#include <math.h>

#define BATCH 512
#define CCH   64
#define NND   32
#define VOC   100
#define DEMB  32
#define HID   64
#define NEDGE 256
#define NT    37
#define NTH   512

// r9 post-mortem: occupancy was GRID-limited (512 blocks = 2/CU, 4 waves/block
// -> 8 waves/CU = 25% cap; measured 21.6%). This version: 512 threads/block
// (8 waves/block, 2 blocks/CU -> 16 waves/CU = 50% cap), which also halves
// each thread's serial chain in the WL and gate phases. __expf for transcend.
__global__ __launch_bounds__(NTH, 4)
void a3_fused_w8(const int* __restrict__ xbg, const int* __restrict__ LOSb,
                 const int* __restrict__ tei, const float* __restrict__ emb,
                 const float* __restrict__ Wz, const float* __restrict__ bz,
                 const float* __restrict__ Wh, const float* __restrict__ bh,
                 const float* __restrict__ Lz, const float* __restrict__ lbz,
                 const float* __restrict__ Lh, const float* __restrict__ lbh,
                 const float* __restrict__ att,
                 const float* __restrict__ Wc1, const float* __restrict__ bc1,
                 const float* __restrict__ Wc2, const float* __restrict__ bc2,
                 float* __restrict__ out) {
    __shared__ float sA[NND][NND];          // 4 KB
    __shared__ float xe[CCH][DEMB];         // 8 KB
    __shared__ float xa[CCH][DEMB];         // 8 KB
    __shared__ float sWL[2][DEMB][HID];     // 16 KB
    __shared__ float scb[2][HID];           // 512 B
    __shared__ float satt[NT];
    __shared__ int   xb[CCH];
    __shared__ int   sdeg[NND];
    __shared__ float sdinv[NND];
    __shared__ float part[8][HID];          // 2 KB
    __shared__ float pooled[HID];
    __shared__ float h1s[2 * HID];

    const int b   = blockIdx.x;
    const int tid = threadIdx.x;
    const int hd  = tid & 63;
    const int wv  = tid >> 6;               // wave id 0..7

    // ---- stage small per-batch + graph data ----
    if (tid < CCH) xb[tid] = xbg[b * CCH + tid];
    if (tid < NT)  satt[tid] = att[tid];
    if (tid < NND) sdeg[tid] = 1;                       // self-loop
#pragma unroll
    for (int i = 0; i < 2; ++i) ((float*)sA)[tid + NTH * i] = 0.f;
    int s_e = 0, d_e = 0;
    if (tid < NEDGE) { s_e = tei[tid]; d_e = tei[NEDGE + tid]; }
    __syncthreads();

    if (tid < NEDGE) atomicAdd(&sdeg[d_e], 1);
    // embedding gather: 2048 elems, 4/thread
#pragma unroll
    for (int i = 0; i < 4; ++i) {
        const int el = tid + NTH * i;
        const int c = el >> 5, k = el & 31;
        xe[c][k] = emb[(c * VOC + xb[c]) * DEMB + k];
    }
    __syncthreads();
    if (tid < NND) sdinv[tid] = rsqrtf((float)sdeg[tid]);
    __syncthreads();
    if (tid < NEDGE) atomicAdd(&sA[d_e][s_e], sdinv[s_e] * sdinv[d_e]);
    if (tid < NND) atomicAdd(&sA[tid][tid], sdinv[tid] * sdinv[tid]);

    // ---- WL = W @ L[:64]  (both gates); 4 e-rows/thread, wave-uniform W ----
    {
        float az[4], ah[4];
#pragma unroll
        for (int i = 0; i < 4; ++i) { az[i] = 0.f; ah[i] = 0.f; }
#pragma unroll 4
        for (int k = 0; k < HID; ++k) {
            const float lz = Lz[k * HID + hd];          // coalesced
            const float lh = Lh[k * HID + hd];
#pragma unroll
            for (int i = 0; i < 4; ++i) {
                const int e = wv + 8 * i;
                az[i] = fmaf(Wz[e * HID + k], lz, az[i]);   // wave-uniform scalar
                ah[i] = fmaf(Wh[e * HID + k], lh, ah[i]);
            }
        }
#pragma unroll
        for (int i = 0; i < 4; ++i) {
            sWL[0][wv + 8 * i][hd] = az[i];
            sWL[1][wv + 8 * i][hd] = ah[i];
        }
    }

    // ---- cb = b @ L[:64] + lb ----
    if (tid < 2 * HID) {
        const int g = tid >> 6, c = tid & 63;
        const float* Lg  = g ? Lh  : Lz;
        const float* bg  = g ? bh  : bz;
        const float* lbg = g ? lbh : lbz;
        float s = lbg[c];
#pragma unroll 4
        for (int k = 0; k < HID; ++k) s = fmaf(bg[k], Lg[k * HID + c], s);
        scb[g][c] = s;
    }

    // ---- cA from softmax prefix (redundant per thread, all from LDS) ----
    const int los = LOSb[b];
    float cA;
    {
        float m = satt[0];
        for (int t = 1; t < NT; ++t) m = fmaxf(m, satt[t]);
        float tot = 0.f, pre = 0.f;
        for (int t = 0; t < NT; ++t) {
            const float e = __expf(satt[t] - m);
            tot += e;
            if (t < los) pre += e;
        }
        cA = pre / tot;
    }
    const float cD = 1.0f - cA;
    __syncthreads();

    // ---- xa = Ahat @ xe : 2048 outputs, 4/thread ----
#pragma unroll
    for (int i = 0; i < 4; ++i) {
        const int o = tid + NTH * i;
        const int r = o >> 5, k = o & 31;
        const int n = r & 31, vb = r & 32;
        float s = 0.f;
#pragma unroll
        for (int q = 0; q < NND; ++q) s = fmaf(sA[n][q], xe[vb | q][k], s);
        xa[r][k] = s;
    }
    __syncthreads();

    // ---- gates + weighted accumulate: 8 rows/thread ----
    float psum = 0.f;
#pragma unroll
    for (int j = 0; j < 8; ++j) {
        const int r = wv + 8 * j;                       // 0..63
        float zl = scb[0][hd], hl = scb[1][hd];
#pragma unroll
        for (int k = 0; k < DEMB; ++k) {
            const float x = xa[r][k];                   // wave-uniform broadcast
            zl = fmaf(x, sWL[0][k][hd], zl);
            hl = fmaf(x, sWL[1][k][hd], hl);
        }
        const float Z  = 1.0f / (1.0f + __expf(-zl));
        const float e2 = __expf(2.0f * hl);            // tanh via exp
        const float Ht = (e2 - 1.0f) / (e2 + 1.0f);
        const float w  = (r < NND) ? cA : cD;
        psum = fmaf(w, (1.0f - Z) * Ht, psum);
    }
    part[wv][hd] = psum;
    __syncthreads();

    // ---- pool over nodes ----
    if (tid < HID) {
        float s = 0.f;
#pragma unroll
        for (int g = 0; g < 8; ++g) s += part[g][tid];
        pooled[tid] = s * (1.0f / NND);
    }
    __syncthreads();

    // ---- head ----
    if (tid < 2 * HID) {
        float a = bc1[tid];
#pragma unroll 4
        for (int k = 0; k < HID; ++k) a = fmaf(pooled[k], Wc1[k * 2 * HID + tid], a);
        h1s[tid] = fmaxf(a, 0.f) * Wc2[tid];
    }
    __syncthreads();
    if (tid < 64) {
        float v = h1s[tid] + h1s[tid + 64];
#pragma unroll
        for (int off = 32; off; off >>= 1) v += __shfl_down(v, off);
        if (tid == 0) out[b] = v + bc2[0];
    }
}

extern "C" void kernel_launch(void* const* d_in, const int* in_sizes, int n_in,
                              void* d_out, int out_size, void* d_ws, size_t ws_size,
                              hipStream_t stream) {
    const int*   x_batch = (const int*)d_in[0];
    const int*   LOSb    = (const int*)d_in[1];
    const int*   tei     = (const int*)d_in[2];
    const float* emb     = (const float*)d_in[3];
    const float* Wz      = (const float*)d_in[4];
    const float* bz      = (const float*)d_in[5];
    const float* Wh      = (const float*)d_in[8];
    const float* bh      = (const float*)d_in[9];
    const float* Lz      = (const float*)d_in[10];
    const float* lbz     = (const float*)d_in[11];
    const float* Lh      = (const float*)d_in[14];
    const float* lbh     = (const float*)d_in[15];
    const float* att     = (const float*)d_in[16];
    const float* Wc1     = (const float*)d_in[17];
    const float* bc1     = (const float*)d_in[18];
    const float* Wc2     = (const float*)d_in[19];
    const float* bc2     = (const float*)d_in[20];
    float* outp = (float*)d_out;

    hipLaunchKernelGGL(a3_fused_w8, dim3(BATCH), dim3(NTH), 0, stream,
                       x_batch, LOSb, tei, emb, Wz, bz, Wh, bh, Lz, lbz, Lh, lbh,
                       att, Wc1, bc1, Wc2, bc2, outp);
}